// Round 5
// baseline (31.671 us; speedup 1.0000x reference)
//
#include <hip/hip_runtime.h>
#include <math.h>

#define LOG2E 1.4426950408889634f
#define LN2   0.6931471805599453f

// 13 VALU inst, 3 hardware trans (2x v_exp_f32, 1x v_log_f32).
// Identity: B = max(s,0)+log1p(exp(-|x|)) with s = t ? -x : x  is BOTH the
// stable BCE-with-logits AND -log(pt). pt = exp(-B).
// combined = 0.5*bce + 0.5*0.25*(1-pt)^2*(-log(pt)) = 0.5*B*(1 + 0.25*(1-pt)^2).
// w carries the 0.5 and the temporal reweight: w in {0.5, 0.4}.
__device__ __forceinline__ float elem_loss(float x, int t, float w) {
    const float s  = t ? -x : x;
    const float e  = __builtin_amdgcn_exp2f(fabsf(x) * -LOG2E);   // exp(-|x|)
    const float L  = LN2 * __builtin_amdgcn_logf(1.0f + e);       // log1p(e)
    const float B  = fmaxf(s, 0.0f) + L;                          // bce == -log(pt)
    const float pt = __builtin_amdgcn_exp2f(B * -LOG2E);
    const float om = 1.0f - pt;
    return (w * B) * __builtin_fmaf(0.25f * om, om, 1.0f);
}

__global__ __launch_bounds__(1024) void loss_kernel(
        const float* __restrict__ x, const int* __restrict__ tg,
        float* __restrict__ out, int n8, int n, float invN) {
    const int tid    = blockIdx.x * blockDim.x + threadIdx.x;
    const int stride = gridDim.x * blockDim.x;
    float sum = 0.0f;

    const float4* x4 = reinterpret_cast<const float4*>(x);
    const int4*   t4 = reinterpret_cast<const int4*>(tg);

    for (int i = tid; i < n8; i += stride) {
        const float4 xa = x4[2 * i];
        const float4 xb = x4[2 * i + 1];
        const int4   ta = t4[2 * i];
        const int4   tb = t4[2 * i + 1];

        int P1 = 0, P2 = 0, P3 = 0, P4 = 0, P5 = 0;  // tg[8i-1..8i-5]
        if (i > 0) {
            const int4 pv = t4[2 * i - 1];
            P1 = pv.w; P2 = pv.z; P3 = pv.y; P4 = pv.x;
            P5 = tg[8 * i - 5];                       // L1/L2 hit
        }

        // prefix-ORs for the 5-wide causal window (targets are 0/1)
        const int q2 = P1 | P2, q3 = q2 | P3, q4 = q3 | P4;
        const int s1 = ta.x | ta.y, s2 = s1 | ta.z, s3 = s2 | ta.w;
        const int w0 = q4 | P5;
        const int w1 = ta.x | q4;
        const int w2 = s1 | q3;
        const int w3 = s2 | q2;
        const int w4 = s3 | P1;
        const int w5 = tb.x | s3;
        const int w6 = tb.y | tb.x | ta.w | ta.z | ta.y;
        const int w7 = tb.z | tb.y | tb.x | ta.w | ta.z;

        const float c0 = elem_loss(xa.x, ta.x, (ta.x & w0) ? 0.4f : 0.5f);
        const float c1 = elem_loss(xa.y, ta.y, (ta.y & w1) ? 0.4f : 0.5f);
        const float c2 = elem_loss(xa.z, ta.z, (ta.z & w2) ? 0.4f : 0.5f);
        const float c3 = elem_loss(xa.w, ta.w, (ta.w & w3) ? 0.4f : 0.5f);
        const float c4 = elem_loss(xb.x, tb.x, (tb.x & w4) ? 0.4f : 0.5f);
        const float c5 = elem_loss(xb.y, tb.y, (tb.y & w5) ? 0.4f : 0.5f);
        const float c6 = elem_loss(xb.z, tb.z, (tb.z & w6) ? 0.4f : 0.5f);
        const float c7 = elem_loss(xb.w, tb.w, (tb.w & w7) ? 0.4f : 0.5f);

        sum += ((c0 + c1) + (c2 + c3)) + ((c4 + c5) + (c6 + c7));
    }

    // scalar tail for n not divisible by 8
    for (int g = 8 * n8 + tid; g < n; g += stride) {
        const int t = tg[g];
        int any = 0;
        #pragma unroll
        for (int k = 1; k <= 5; ++k) if (g - k >= 0) any |= tg[g - k];
        sum += elem_loss(x[g], t, (t & any) ? 0.4f : 0.5f);
    }

    // wave (64-lane) shfl reduction, then LDS across 16 waves
    #pragma unroll
    for (int off = 32; off > 0; off >>= 1) sum += __shfl_down(sum, off);
    __shared__ float wsum[16];
    const int lane = threadIdx.x & 63;
    const int wid  = threadIdx.x >> 6;
    if (lane == 0) wsum[wid] = sum;
    __syncthreads();
    if (threadIdx.x == 0) {
        float b = 0.0f;
        #pragma unroll
        for (int k = 0; k < 16; ++k) b += wsum[k];
        // relaxed HW fp32 atomic (global_atomic_add_f32): no fence, no
        // serialization cliff (cf. round-3's acq_rel RMW disaster).
        unsafeAtomicAdd(out, b * invN);
    }
}

extern "C" void kernel_launch(void* const* d_in, const int* in_sizes, int n_in,
                              void* d_out, int out_size, void* d_ws, size_t ws_size,
                              hipStream_t stream) {
    const float* x  = (const float*)d_in[0];
    const int*   tg = (const int*)d_in[1];
    float* out      = (float*)d_out;

    const int n  = in_sizes[0];
    const int n8 = n / 8;

    // accumulate into d_out: zero it each call (async memset is graph-safe)
    hipMemsetAsync(out, 0, sizeof(float), stream);
    // 512 blocks x 1024 threads = 2 wg/CU = 32 waves/CU (max occupancy);
    // only 512 same-address atomics, spread over block completion.
    loss_kernel<<<512, 1024, 0, stream>>>(x, tg, out, n8, n, 1.0f / (float)n);
}

// Round 6
// 30.663 us; speedup vs baseline: 1.0329x; 1.0329x over previous
//
#include <hip/hip_runtime.h>
#include <math.h>

#define LOG2E 1.4426950408889634f
#define LN2   0.6931471805599453f

// 13 VALU inst, 3 hardware trans (2x v_exp_f32, 1x v_log_f32).
// Identity: B = max(s,0)+log1p(exp(-|x|)) with s = t ? -x : x  is BOTH the
// stable BCE-with-logits AND -log(pt). pt = exp(-B).
// combined = 0.5*B*(1 + 0.25*(1-pt)^2); w carries 0.5 and temporal reweight.
__device__ __forceinline__ float elem_loss(float x, int t, float w) {
    const float s  = t ? -x : x;
    const float e  = __builtin_amdgcn_exp2f(fabsf(x) * -LOG2E);   // exp(-|x|)
    const float L  = LN2 * __builtin_amdgcn_logf(1.0f + e);       // log1p(e)
    const float B  = fmaxf(s, 0.0f) + L;                          // bce == -log(pt)
    const float pt = __builtin_amdgcn_exp2f(B * -LOG2E);
    const float om = 1.0f - pt;
    return (w * B) * __builtin_fmaf(0.25f * om, om, 1.0f);
}

__global__ __launch_bounds__(256) void loss_partial_kernel(
        const float* __restrict__ x, const int* __restrict__ tg,
        float* __restrict__ partial, int n8, int n) {
    const int tid    = blockIdx.x * blockDim.x + threadIdx.x;
    const int stride = gridDim.x * blockDim.x;
    const int lane   = threadIdx.x & 63;
    float sum = 0.0f;

    const float4* x4 = reinterpret_cast<const float4*>(x);
    const int4*   t4 = reinterpret_cast<const int4*>(tg);

    for (int i = tid; i < n8; i += stride) {
        // 4 VMEM per iteration (was 6): window comes from the neighbor lane.
        const float4 xa = x4[2 * i];
        const float4 xb = x4[2 * i + 1];
        const int4   ta = t4[2 * i];
        const int4   tb = t4[2 * i + 1];

        // pack this group's 8 target bits: bit j = targets[8i+j]
        const int b = ta.x | (ta.y << 1) | (ta.z << 2) | (ta.w << 3)
                    | (tb.x << 4) | (tb.y << 5) | (tb.z << 6) | (tb.w << 7);

        // previous group's byte: consecutive lanes hold consecutive groups
        int prev = __shfl_up(b, 1);
        if (lane == 0) {
            prev = 0;
            if (i > 0) {                       // 1-lane predicated fallback
                const int4 pv = t4[2 * i - 1];
                prev = (tg[8 * i - 5] << 3) | (pv.x << 4) | (pv.y << 5)
                     | (pv.z << 6) | (pv.w << 7);
            }
        }
        // W bit k = targets[8i-8+k]; element j is bit 8+j; its 5-wide causal
        // window is bits [3+j .. 7+j]
        const int W = prev | (b << 8);

        float s8 = 0.0f;
        #pragma unroll
        for (int j = 0; j < 8; ++j) {
            const float xv = (j < 4) ? ((const float*)&xa)[j] : ((const float*)&xb)[j - 4];
            const int   t  = (b >> j) & 1;
            const int   hit = t & (((W >> (3 + j)) & 31) ? 1 : 0);
            s8 += elem_loss(xv, t, hit ? 0.4f : 0.5f);
        }
        sum += s8;
    }

    // scalar tail for n not divisible by 8
    for (int g = 8 * n8 + tid; g < n; g += stride) {
        const int t = tg[g];
        int any = 0;
        #pragma unroll
        for (int k = 1; k <= 5; ++k) if (g - k >= 0) any |= tg[g - k];
        sum += elem_loss(x[g], t, (t & (any ? 1 : 0)) ? 0.4f : 0.5f);
    }

    // wave (64-lane) shfl reduction, then LDS across 4 waves
    #pragma unroll
    for (int off = 32; off > 0; off >>= 1) sum += __shfl_down(sum, off);
    __shared__ float wsum[4];
    const int wid = threadIdx.x >> 6;
    if (lane == 0) wsum[wid] = sum;
    __syncthreads();
    if (threadIdx.x == 0)
        partial[blockIdx.x] = (wsum[0] + wsum[1]) + (wsum[2] + wsum[3]);
}

__global__ __launch_bounds__(256) void final_reduce_kernel(
        const float* __restrict__ partial, int nb,
        float* __restrict__ out, float invN) {
    float s = 0.0f;
    for (int i = threadIdx.x; i < nb; i += 256) s += partial[i];
    #pragma unroll
    for (int off = 32; off > 0; off >>= 1) s += __shfl_down(s, off);
    __shared__ float wsum[4];
    const int lane = threadIdx.x & 63;
    const int wid  = threadIdx.x >> 6;
    if (lane == 0) wsum[wid] = s;
    __syncthreads();
    if (threadIdx.x == 0)
        out[0] = ((wsum[0] + wsum[1]) + (wsum[2] + wsum[3])) * invN;
}

extern "C" void kernel_launch(void* const* d_in, const int* in_sizes, int n_in,
                              void* d_out, int out_size, void* d_ws, size_t ws_size,
                              hipStream_t stream) {
    const float* x  = (const float*)d_in[0];
    const int*   tg = (const int*)d_in[1];
    float* out      = (float*)d_out;
    float* partial  = (float*)d_ws;

    const int n  = in_sizes[0];
    const int n8 = n / 8;
    const int NB = 2048;   // 8 wg/CU = 32 waves/CU; grid-stride the rest

    loss_partial_kernel<<<NB, 256, 0, stream>>>(x, tg, partial, n8, n);
    final_reduce_kernel<<<1, 256, 0, stream>>>(partial, NB, out, 1.0f / (float)n);
}